// Round 12
// baseline (2526.500 us; speedup 1.0000x reference)
//
#include <hip/hip_runtime.h>

#define N_NODES 50000
#define DIM 128
#define D8 16            // DIM/8 (uint4 = 8 bf16 chunks per row)
#define N_EDGES 800000
#define N_LAYERS 3
#define BN_EPS 1e-5f
#define NREP 16                              // stat replicas (atomic-chain breaker)
#define STSZ (256 * NREP)                    // floats per stat set
#define CHUNK 4096
#define NCHUNK ((N_EDGES + CHUNK - 1) / CHUNK)   // 196
#define EPT (CHUNK / 256)                        // 16
#define BUCK_SH 7
#define BUCK_N 128
#define NBUCK ((N_NODES + BUCK_N - 1) / BUCK_N)  // 391

typedef __attribute__((ext_vector_type(8))) short bf16x8;
typedef __attribute__((ext_vector_type(4))) float f32x4;

// fp32 -> bf16 round-to-nearest-even
__device__ __forceinline__ unsigned short f2bf(float f) {
    unsigned int u = __float_as_uint(f);
    u = (u + 0x7FFFu + ((u >> 16) & 1u)) >> 16;
    return (unsigned short)u;
}
__device__ __forceinline__ unsigned int pack2(float a, float b) {
    return (unsigned int)f2bf(a) | ((unsigned int)f2bf(b) << 16);
}
// fp32 <-> fp16 (RTE via native cast)
__device__ __forceinline__ unsigned short f2h(float f) {
    _Float16 h = (_Float16)f;
    unsigned short u;
    __builtin_memcpy(&u, &h, 2);
    return u;
}
__device__ __forceinline__ float h2f(unsigned short u) {
    _Float16 h;
    __builtin_memcpy(&h, &u, 2);
    return (float)h;
}

// scale/shift from raw BN stats
__device__ __forceinline__ void bn_coef(float sum, float sq, float g, float b,
                                        float& sc, float& sh) {
    float mean = sum * (1.f / N_NODES);
    float var  = sq * (1.f / N_NODES) - mean * mean;
    float rstd = rsqrtf(var + BN_EPS);
    sc = g * rstd;
    sh = b - mean * sc;
}

// sum NREP replicas, then coefs (vector form; cg = float4 column group)
__device__ __forceinline__ void bn_coef4(const float* st,
                                         const float* g, const float* b, int cg,
                                         float4& sc, float4& sh) {
    float4 s = make_float4(0.f, 0.f, 0.f, 0.f);
    float4 q = make_float4(0.f, 0.f, 0.f, 0.f);
    #pragma unroll
    for (int r = 0; r < NREP; r++) {
        const float4* p = reinterpret_cast<const float4*>(st + r * 256);
        float4 a = p[cg];          // sum part
        float4 c = p[32 + cg];     // sq part
        s.x += a.x; s.y += a.y; s.z += a.z; s.w += a.w;
        q.x += c.x; q.y += c.y; q.z += c.z; q.w += c.w;
    }
    float4 gg = reinterpret_cast<const float4*>(g)[cg];
    float4 bb = reinterpret_cast<const float4*>(b)[cg];
    bn_coef(s.x, q.x, gg.x, bb.x, sc.x, sh.x);
    bn_coef(s.y, q.y, gg.y, bb.y, sc.y, sh.y);
    bn_coef(s.z, q.z, gg.z, bb.z, sc.z, sh.z);
    bn_coef(s.w, q.w, gg.w, bb.w, sc.w, sh.w);
}

// ---------------- W transpose + bf16 convert (once per launch, all 6 weights) ----
__global__ __launch_bounds__(256) void wt_kernel(
    const float* __restrict__ W1, const float* __restrict__ W2,
    unsigned short* __restrict__ wtg)
{
    int tid = blockIdx.x * 256 + threadIdx.x;          // 6*16384 total
    if (tid >= 6 * DIM * DIM) return;
    int m = tid >> 14;           // /16384
    int r = tid & 16383;
    int c = r >> 7;              // output row (col of W)
    int k = r & 127;             // output col (row of W)
    const float* src = (m < 3) ? (W1 + (size_t)m * DIM * DIM)
                               : (W2 + (size_t)(m - 3) * DIM * DIM);
    wtg[tid] = f2bf(src[k * DIM + c]);
}

// ---------------- h0 fp32 -> bf16 (layer 0 only) ----------------
__global__ __launch_bounds__(256) void conv0_kernel(
    const float* __restrict__ h, unsigned short* __restrict__ hbf)
{
    int idx = blockIdx.x * 256 + threadIdx.x;          // per 8 elems
    if (idx >= N_NODES * D8) return;
    const float4* h4 = reinterpret_cast<const float4*>(h);
    float4 a = h4[idx * 2], b = h4[idx * 2 + 1];
    uint4 p;
    p.x = pack2(a.x, a.y); p.y = pack2(a.z, a.w);
    p.z = pack2(b.x, b.y); p.w = pack2(b.z, b.w);
    reinterpret_cast<uint4*>(hbf)[idx] = p;
}

// ---- A: per-chunk bucket histogram -> matA[c][b] (coalesced) ----
__global__ __launch_bounds__(256) void binhist_kernel(
    const int* __restrict__ dst, int* __restrict__ matA)
{
    __shared__ int lh[NBUCK];
    int t = threadIdx.x, c = blockIdx.x;
    for (int b = t; b < NBUCK; b += 256) lh[b] = 0;
    __syncthreads();
    int base = c * CHUNK;
    #pragma unroll
    for (int i = 0; i < EPT; i++) {
        int e = base + i * 256 + t;
        if (e < N_EDGES) atomicAdd(&lh[dst[e] >> BUCK_SH], 1);
    }
    __syncthreads();
    for (int b = t; b < NBUCK; b += 256) matA[c * NBUCK + b] = lh[b];
}

// ---- B: per-bucket column scan over chunks -> matoffT[b][c], btot[b] ----
__global__ __launch_bounds__(256) void colscan_kernel(
    const int* __restrict__ matA, int* __restrict__ matoffT, int* __restrict__ btot)
{
    __shared__ int s[256];
    int t = threadIdx.x, b = blockIdx.x;
    int v = (t < NCHUNK) ? matA[t * NBUCK + b] : 0;
    s[t] = v;
    __syncthreads();
    #pragma unroll
    for (int off = 1; off < 256; off <<= 1) {
        int u = (t >= off) ? s[t - off] : 0;
        __syncthreads();
        s[t] += u;
        __syncthreads();
    }
    if (t < NCHUNK) matoffT[b * NCHUNK + t] = s[t] - v;   // exclusive
    if (t == 255) btot[b] = s[255];
}

// ---- C: scan bucket totals -> bbase[b] ----
__global__ __launch_bounds__(512) void bucketbase_kernel(
    const int* __restrict__ btot, int* __restrict__ bbase)
{
    __shared__ int s[512];
    int t = threadIdx.x;
    int v = (t < NBUCK) ? btot[t] : 0;
    s[t] = v;
    __syncthreads();
    #pragma unroll
    for (int off = 1; off < 512; off <<= 1) {
        int u = (t >= off) ? s[t - off] : 0;
        __syncthreads();
        s[t] += u;
        __syncthreads();
    }
    if (t < NBUCK) bbase[t] = s[t] - v;                   // exclusive
}

// ---- D: deterministic binned fill. record = (src<<16|fp16(w), dst&127) ----
// Writes land in contiguous per-(chunk,bucket) runs (no global atomics).
__global__ __launch_bounds__(256) void binfill_kernel(
    const int* __restrict__ src, const int* __restrict__ dst,
    const float* __restrict__ ew, const int* __restrict__ matoffT,
    const int* __restrict__ bbase, uint2* __restrict__ erec)
{
    __shared__ int lh[NBUCK];
    __shared__ int loff[NBUCK];
    int t = threadIdx.x, c = blockIdx.x;
    for (int b = t; b < NBUCK; b += 256) {
        lh[b] = 0;
        loff[b] = bbase[b] + matoffT[b * NCHUNK + c];
    }
    __syncthreads();
    int base = c * CHUNK;
    #pragma unroll
    for (int i = 0; i < EPT; i++) {
        int e = base + i * 256 + t;
        if (e < N_EDGES) {
            int d = dst[e];
            int b = d >> BUCK_SH;
            int lp = atomicAdd(&lh[b], 1);
            erec[loff[b] + lp] = make_uint2(
                ((unsigned int)src[e] << 16) | (unsigned int)f2h(ew[e]),
                (unsigned int)(d & (BUCK_N - 1)));
        }
    }
}

// ---- E: bucket aggregation with LDS fp32 accumulator ----
// acc[r][:] = h[node0+r] (self term), then += w * h[src] per record; write rbf.
__global__ __launch_bounds__(256) void aggb_kernel(
    const unsigned int* __restrict__ h_u, const uint2* __restrict__ erec,
    const int* __restrict__ bbase, const int* __restrict__ btot,
    unsigned int* __restrict__ r_u)
{
    __shared__ float acc[BUCK_N * DIM];   // 64 KB
    int t = threadIdx.x, b = blockIdx.x;
    int node0 = b * BUCK_N;
    for (int id = t; id < BUCK_N * 64; id += 256) {
        int r = id >> 6, cu = id & 63;
        float f0 = 0.f, f1 = 0.f;
        if (node0 + r < N_NODES) {
            unsigned int u = h_u[(size_t)(node0 + r) * 64 + cu];
            f0 = __uint_as_float(u << 16);
            f1 = __uint_as_float(u & 0xFFFF0000u);
        }
        acc[r * DIM + cu * 2]     = f0;
        acc[r * DIM + cu * 2 + 1] = f1;
    }
    __syncthreads();
    int beg = bbase[b], cnt = btot[b];
    int wv = t >> 6, ln = t & 63;
    for (int j = wv; j < cnt; j += 4) {
        uint2 rec = erec[beg + j];
        float w = h2f((unsigned short)(rec.x & 0xFFFFu));
        int srcn = (int)(rec.x >> 16);
        int dl = (int)rec.y;
        unsigned int u = h_u[(size_t)srcn * 64 + ln];
        atomicAdd(&acc[dl * DIM + ln * 2],     w * __uint_as_float(u << 16));
        atomicAdd(&acc[dl * DIM + ln * 2 + 1], w * __uint_as_float(u & 0xFFFF0000u));
    }
    __syncthreads();
    for (int id = t; id < BUCK_N * 64; id += 256) {
        int r = id >> 6, cu = id & 63;
        if (node0 + r < N_NODES)
            r_u[(size_t)(node0 + r) * 64 + cu] =
                pack2(acc[r * DIM + cu * 2], acc[r * DIM + cu * 2 + 1]);
    }
}

// ---------------- MFMA GEMM: out = f(in) @ W + bias, + column stats ----------------
// MODE 0: in = rbf (pre-staged bf16)     (GEMM1)
// MODE 1: in = relu(BN(A; st,g,b))       (GEMM2: BN1+ReLU fused on staging)
template<int MODE>
__global__ __launch_bounds__(256) void gemm_kernel(
    const unsigned short* __restrict__ Abf, const float* __restrict__ A,
    const float* __restrict__ st_in, const float* __restrict__ bn_g,
    const float* __restrict__ bn_b,
    const unsigned short* __restrict__ Wt, const float* __restrict__ bias,
    float* __restrict__ out, float* __restrict__ st_out)
{
    __shared__ unsigned short A_sm[64 * DIM];    // 16 KB bf16, XOR-swizzled
    __shared__ unsigned short W_sm[DIM * DIM];   // 32 KB bf16 W^T, XOR-swizzled
    __shared__ float2 scsh[DIM];                 // BN coefs (MODE 1)

    const int t = threadIdx.x;
    const int row0 = blockIdx.x * 64;

    if (MODE == 1) {
        if (t < 128) {
            float ssum = 0.f, ssq = 0.f;
            #pragma unroll
            for (int r = 0; r < NREP; r++) {
                ssum += st_in[r * 256 + t];
                ssq  += st_in[r * 256 + 128 + t];
            }
            float sc, sh;
            bn_coef(ssum, ssq, bn_g[t], bn_b[t], sc, sh);
            scsh[t] = make_float2(sc, sh);
        }
        __syncthreads();
    }

    // ---- stage W^T (already bf16, c-major): 2048 16B chunks ----
    {
        const uint4* wsrc = reinterpret_cast<const uint4*>(Wt);
        #pragma unroll
        for (int j = 0; j < 8; j++) {
            int id = t + j * 256;            // 0..2047
            int c  = id >> 4;
            int kc = id & 15;
            int sidx = (c * DIM + kc * 8) ^ ((c & 7) << 3);
            *reinterpret_cast<uint4*>(&W_sm[sidx]) = wsrc[id];
        }
    }

    // ---- stage A tile (swizzled) ----
    if (MODE == 0) {
        const uint4* asrc = reinterpret_cast<const uint4*>(Abf);
        #pragma unroll
        for (int j = 0; j < 4; j++) {
            int id = t + j * 256;            // 0..1023
            int r  = id >> 4;                // tile row 0..63
            int kc = id & 15;
            int row = row0 + r;
            uint4 u = make_uint4(0u, 0u, 0u, 0u);
            if (row < N_NODES) u = asrc[row * D8 + kc];
            int sidx = (r * DIM + kc * 8) ^ ((r & 7) << 3);
            *reinterpret_cast<uint4*>(&A_sm[sidx]) = u;
        }
    } else {
        const float4* A4 = reinterpret_cast<const float4*>(A);
        #pragma unroll
        for (int j = 0; j < 8; j++) {
            int id = t + j * 256;            // 0..2047
            int r  = id >> 5;                // tile row 0..63
            int q  = id & 31;                // float4 col group
            int row = row0 + r;
            float4 v = make_float4(0.f, 0.f, 0.f, 0.f);
            if (row < N_NODES) {
                float4 a = A4[(size_t)row * 32 + q];
                float2 c0 = scsh[q * 4 + 0], c1 = scsh[q * 4 + 1];
                float2 c2 = scsh[q * 4 + 2], c3 = scsh[q * 4 + 3];
                v.x = fmaxf(fmaf(a.x, c0.x, c0.y), 0.f);
                v.y = fmaxf(fmaf(a.y, c1.x, c1.y), 0.f);
                v.z = fmaxf(fmaf(a.z, c2.x, c2.y), 0.f);
                v.w = fmaxf(fmaf(a.w, c3.x, c3.y), 0.f);
            }
            ushort4 u = make_ushort4(f2bf(v.x), f2bf(v.y), f2bf(v.z), f2bf(v.w));
            int sidx = (r * DIM + q * 4) ^ ((r & 7) << 3);
            *reinterpret_cast<ushort4*>(&A_sm[sidx]) = u;
        }
    }
    __syncthreads();

    // ---- MFMA: wave w owns rows w*16..w*16+15, all 8 col-blocks ----
    const int w    = t >> 6;
    const int lane = t & 63;
    const int lrow = lane & 15;
    const int lkg  = lane >> 4;
    const int arow = w * 16 + lrow;

    bf16x8 afr[4];
    #pragma unroll
    for (int ks = 0; ks < 4; ks++) {
        int k = ks * 32 + lkg * 8;
        int idx = (arow * DIM + k) ^ ((arow & 7) << 3);
        afr[ks] = *reinterpret_cast<const bf16x8*>(&A_sm[idx]);
    }

    f32x4 acc[8];
    #pragma unroll
    for (int cb = 0; cb < 8; cb++) {
        f32x4 a = {0.f, 0.f, 0.f, 0.f};
        int col = cb * 16 + lrow;
        #pragma unroll
        for (int ks = 0; ks < 4; ks++) {
            int k = ks * 32 + lkg * 8;
            int widx = (col * DIM + k) ^ ((col & 7) << 3);
            bf16x8 bfr = *reinterpret_cast<const bf16x8*>(&W_sm[widx]);
            a = __builtin_amdgcn_mfma_f32_16x16x32_bf16(afr[ks], bfr, a, 0, 0, 0);
        }
        acc[cb] = a;
    }

    // ---- epilogue: bias add, store, column stats ----
    float s_c[8], q_c[8];
    #pragma unroll
    for (int cb = 0; cb < 8; cb++) {
        int col = cb * 16 + lrow;
        float bc = bias[col];
        float s = 0.f, q = 0.f;
        #pragma unroll
        for (int r = 0; r < 4; r++) {
            int row = row0 + w * 16 + lkg * 4 + r;
            if (row < N_NODES) {
                float v = acc[cb][r] + bc;
                out[(size_t)row * DIM + col] = v;
                s += v; q += v * v;
            }
        }
        s_c[cb] = s; q_c[cb] = q;
    }
    #pragma unroll
    for (int cb = 0; cb < 8; cb++) {
        s_c[cb] += __shfl_xor(s_c[cb], 16); s_c[cb] += __shfl_xor(s_c[cb], 32);
        q_c[cb] += __shfl_xor(q_c[cb], 16); q_c[cb] += __shfl_xor(q_c[cb], 32);
    }
    __syncthreads();                 // done with A_sm, reuse as reduce scratch
    float* red = reinterpret_cast<float*>(A_sm);   // [4 waves][2][128]
    if (lkg == 0) {
        #pragma unroll
        for (int cb = 0; cb < 8; cb++) {
            red[w * 256 + cb * 16 + lrow]       = s_c[cb];
            red[w * 256 + 128 + cb * 16 + lrow] = q_c[cb];
        }
    }
    __syncthreads();
    float* strep = st_out + (blockIdx.x & (NREP - 1)) * 256;
    if (t < 256) {
        float v = red[t] + red[256 + t] + red[512 + t] + red[768 + t];
        unsafeAtomicAdd(&strep[t], v);
    }
}

// ---------------- stats of xa = relu(BN(x; stA)) — no data write ----------------
__global__ __launch_bounds__(256) void bn_stats_kernel(
    const float* __restrict__ x, const float* __restrict__ st_in,
    const float* __restrict__ bn_g, const float* __restrict__ bn_b,
    float* __restrict__ st_out)
{
    const int t = threadIdx.x;
    const int cg = t & 31;
    float4 sc, sh;
    bn_coef4(st_in, bn_g, bn_b, cg, sc, sh);
    const float4* x4 = reinterpret_cast<const float4*>(x);
    float4 psum = make_float4(0.f, 0.f, 0.f, 0.f);
    float4 psq  = make_float4(0.f, 0.f, 0.f, 0.f);
    const int total = N_NODES * 32;
    const int stride = gridDim.x * 256;
    for (int idx = blockIdx.x * 256 + t; idx < total; idx += stride) {
        float4 v = x4[idx];
        v.x = fmaxf(fmaf(v.x, sc.x, sh.x), 0.f);
        v.y = fmaxf(fmaf(v.y, sc.y, sh.y), 0.f);
        v.z = fmaxf(fmaf(v.z, sc.z, sh.z), 0.f);
        v.w = fmaxf(fmaf(v.w, sc.w, sh.w), 0.f);
        psum.x += v.x; psum.y += v.y; psum.z += v.z; psum.w += v.w;
        psq.x += v.x * v.x; psq.y += v.y * v.y; psq.z += v.z * v.z; psq.w += v.w * v.w;
    }
    __shared__ float4 red[512];
    red[t]       = psum;
    red[256 + t] = psq;
    __syncthreads();
    if (t < 32) {
        float4 s = make_float4(0.f, 0.f, 0.f, 0.f);
        float4 q = make_float4(0.f, 0.f, 0.f, 0.f);
        #pragma unroll
        for (int r = 0; r < 8; r++) {
            float4 a = red[r * 32 + t];
            float4 b = red[256 + r * 32 + t];
            s.x += a.x; s.y += a.y; s.z += a.z; s.w += a.w;
            q.x += b.x; q.y += b.y; q.z += b.z; q.w += b.w;
        }
        float* strep = st_out + (blockIdx.x & (NREP - 1)) * 256;
        float* gs = strep + t * 4;
        float* gq = strep + 128 + t * 4;
        unsafeAtomicAdd(gs + 0, s.x); unsafeAtomicAdd(gs + 1, s.y);
        unsafeAtomicAdd(gs + 2, s.z); unsafeAtomicAdd(gs + 3, s.w);
        unsafeAtomicAdd(gq + 0, q.x); unsafeAtomicAdd(gq + 1, q.y);
        unsafeAtomicAdd(gq + 2, q.z); unsafeAtomicAdd(gq + 3, q.w);
    }
}

// ---------------- h = relu(BN_o(relu(BN_a(x)))) ----------------
// LAST=0: write bf16 h only (next layer input). LAST=1: write fp32 d_out only.
template<int LAST>
__global__ __launch_bounds__(256) void bn_final_kernel(
    const float* __restrict__ x,
    const float* __restrict__ stA, const float* __restrict__ ga, const float* __restrict__ ba,
    const float* __restrict__ stO, const float* __restrict__ go, const float* __restrict__ bo,
    float* __restrict__ y, unsigned short* __restrict__ ybf)
{
    const int t = threadIdx.x;
    const int cg = t & 31;
    float4 sca, sha, sco, sho;
    bn_coef4(stA, ga, ba, cg, sca, sha);
    bn_coef4(stO, go, bo, cg, sco, sho);
    const float4* x4 = reinterpret_cast<const float4*>(x);
    float4* y4 = reinterpret_cast<float4*>(y);
    const int total = N_NODES * 32;
    const int stride = gridDim.x * 256;
    for (int idx = blockIdx.x * 256 + t; idx < total; idx += stride) {
        float4 v = x4[idx];
        v.x = fmaxf(fmaf(v.x, sca.x, sha.x), 0.f);
        v.y = fmaxf(fmaf(v.y, sca.y, sha.y), 0.f);
        v.z = fmaxf(fmaf(v.z, sca.z, sha.z), 0.f);
        v.w = fmaxf(fmaf(v.w, sca.w, sha.w), 0.f);
        v.x = fmaxf(fmaf(v.x, sco.x, sho.x), 0.f);
        v.y = fmaxf(fmaf(v.y, sco.y, sho.y), 0.f);
        v.z = fmaxf(fmaf(v.z, sco.z, sho.z), 0.f);
        v.w = fmaxf(fmaf(v.w, sco.w, sho.w), 0.f);
        if (LAST) {
            y4[idx] = v;
        } else {
            ushort4 u = make_ushort4(f2bf(v.x), f2bf(v.y), f2bf(v.z), f2bf(v.w));
            reinterpret_cast<ushort4*>(ybf)[idx] = u;
        }
    }
}

extern "C" void kernel_launch(void* const* d_in, const int* in_sizes, int n_in,
                              void* d_out, int out_size, void* d_ws, size_t ws_size,
                              hipStream_t stream)
{
    const float* h0    = (const float*)d_in[0];
    const int*   src   = (const int*)d_in[1];
    const int*   dst   = (const int*)d_in[2];
    const float* ew    = (const float*)d_in[3];
    const float* W1    = (const float*)d_in[4];
    const float* b1    = (const float*)d_in[5];
    const float* bn1_g = (const float*)d_in[6];
    const float* bn1_b = (const float*)d_in[7];
    const float* W2    = (const float*)d_in[8];
    const float* b2    = (const float*)d_in[9];
    const float* bna_g = (const float*)d_in[10];
    const float* bna_b = (const float*)d_in[11];
    const float* bno_g = (const float*)d_in[12];
    const float* bno_b = (const float*)d_in[13];

    const size_t ND = (size_t)N_NODES * DIM;
    float* R0      = (float*)d_ws;                        // N*D floats
    float* R1      = R0 + ND;                             // N*D floats
    float* stats   = R1 + ND;                             // 9 * STSZ floats
    int*   matA    = (int*)(stats + 9 * STSZ);            // NCHUNK*NBUCK
    int*   matoffT = matA + NCHUNK * NBUCK;               // NBUCK*NCHUNK
    int*   btot    = matoffT + NBUCK * NCHUNK;            // NBUCK
    int*   bbase   = btot + NBUCK;                        // NBUCK
    uint2* erec    = (uint2*)(((uintptr_t)(bbase + NBUCK) + 15) & ~(uintptr_t)15); // E uint2
    unsigned short* wtg = (unsigned short*)(erec + N_EDGES);   // 6*128*128 bf16
    float* hout    = (float*)d_out;

    hipMemsetAsync(stats, 0, 9 * STSZ * sizeof(float), stream);
    wt_kernel<<<(6 * DIM * DIM + 255) / 256, 256, 0, stream>>>(W1, W2, wtg);
    conv0_kernel<<<(N_NODES * D8 + 255) / 256, 256, 0, stream>>>(h0, (unsigned short*)R0);

    const int gemm_grid = (N_NODES + 63) / 64;            // 782

    for (int i = 0; i < N_LAYERS; i++) {
        const int* srcL = src + (size_t)i * N_EDGES;
        const int* dstL = dst + (size_t)i * N_EDGES;
        const float* ewL = ew + (size_t)i * N_EDGES;
        float* st1 = stats + (size_t)(i * 3 + 0) * STSZ;  // NREP x [sum(128)|sq(128)]
        float* stA = stats + (size_t)(i * 3 + 1) * STSZ;
        float* stO = stats + (size_t)(i * 3 + 2) * STSZ;
        const unsigned short* wt1 = wtg + (size_t)i * DIM * DIM;
        const unsigned short* wt2 = wtg + (size_t)(i + 3) * DIM * DIM;

        // ping-pong regions: even layers h/r in R0, odd layers in R1
        float* Re = (i & 1) ? R1 : R0;
        float* Ro = (i & 1) ? R0 : R1;
        unsigned short* hbf = (unsigned short*)Re;        // first half of Re
        unsigned short* rbf = (unsigned short*)Re + ND;   // second half of Re
        float* x1 = Ro;
        float* x2 = Re;                                   // clobbers hbf+rbf (dead)
        unsigned short* ybf = (unsigned short*)Ro;        // next layer's hbf

        // --- deterministic binned CSR-lite + bucket aggregation ---
        binhist_kernel<<<NCHUNK, 256, 0, stream>>>(dstL, matA);
        colscan_kernel<<<NBUCK, 256, 0, stream>>>(matA, matoffT, btot);
        bucketbase_kernel<<<1, 512, 0, stream>>>(btot, bbase);
        binfill_kernel<<<NCHUNK, 256, 0, stream>>>(srcL, dstL, ewL, matoffT, bbase, erec);
        aggb_kernel<<<NBUCK, 256, 0, stream>>>(
            (const unsigned int*)hbf, erec, bbase, btot, (unsigned int*)rbf);

        gemm_kernel<0><<<gemm_grid, 256, 0, stream>>>(
            rbf, nullptr, nullptr, nullptr, nullptr,
            wt1, b1 + (size_t)i * DIM, x1, st1);

        gemm_kernel<1><<<gemm_grid, 256, 0, stream>>>(
            nullptr, x1, st1, bn1_g + (size_t)i * DIM, bn1_b + (size_t)i * DIM,
            wt2, b2 + (size_t)i * DIM, x2, stA);

        bn_stats_kernel<<<1024, 256, 0, stream>>>(
            x2, stA, bna_g + (size_t)i * DIM, bna_b + (size_t)i * DIM, stO);

        if (i == N_LAYERS - 1) {
            bn_final_kernel<1><<<1024, 256, 0, stream>>>(
                x2, stA, bna_g + (size_t)i * DIM, bna_b + (size_t)i * DIM,
                stO, bno_g + (size_t)i * DIM, bno_b + (size_t)i * DIM, hout, nullptr);
        } else {
            bn_final_kernel<0><<<1024, 256, 0, stream>>>(
                x2, stA, bna_g + (size_t)i * DIM, bna_b + (size_t)i * DIM,
                stO, bno_g + (size_t)i * DIM, bno_b + (size_t)i * DIM, nullptr, ybf);
        }
    }
}

// Round 13
// 2522.792 us; speedup vs baseline: 1.0015x; 1.0015x over previous
//
#include <hip/hip_runtime.h>

#define N_NODES 50000
#define DIM 128
#define D8 16            // DIM/8 (uint4 = 8 bf16 chunks per row)
#define N_EDGES 800000
#define N_LAYERS 3
#define BN_EPS 1e-5f
#define NREP 16                              // stat replicas (atomic-chain breaker)
#define STSZ (256 * NREP)                    // floats per stat set
#define CHUNK 4096
#define NCHUNK ((N_EDGES + CHUNK - 1) / CHUNK)   // 196
#define EPT (CHUNK / 256)                        // 16
#define BUCK_SH 7
#define BUCK_N 128
#define NBUCK ((N_NODES + BUCK_N - 1) / BUCK_N)  // 391
#define AGG_T 512                                // aggb threads (8 waves)
#define AGG_U 8                                  // prefetch depth (records/wave/batch)

typedef __attribute__((ext_vector_type(8))) short bf16x8;
typedef __attribute__((ext_vector_type(4))) float f32x4;

// fp32 -> bf16 round-to-nearest-even
__device__ __forceinline__ unsigned short f2bf(float f) {
    unsigned int u = __float_as_uint(f);
    u = (u + 0x7FFFu + ((u >> 16) & 1u)) >> 16;
    return (unsigned short)u;
}
__device__ __forceinline__ unsigned int pack2(float a, float b) {
    return (unsigned int)f2bf(a) | ((unsigned int)f2bf(b) << 16);
}
// fp32 <-> fp16 (RTE via native cast)
__device__ __forceinline__ unsigned short f2h(float f) {
    _Float16 h = (_Float16)f;
    unsigned short u;
    __builtin_memcpy(&u, &h, 2);
    return u;
}
__device__ __forceinline__ float h2f(unsigned short u) {
    _Float16 h;
    __builtin_memcpy(&h, &u, 2);
    return (float)h;
}

// scale/shift from raw BN stats
__device__ __forceinline__ void bn_coef(float sum, float sq, float g, float b,
                                        float& sc, float& sh) {
    float mean = sum * (1.f / N_NODES);
    float var  = sq * (1.f / N_NODES) - mean * mean;
    float rstd = rsqrtf(var + BN_EPS);
    sc = g * rstd;
    sh = b - mean * sc;
}

// sum NREP replicas, then coefs (vector form; cg = float4 column group)
__device__ __forceinline__ void bn_coef4(const float* st,
                                         const float* g, const float* b, int cg,
                                         float4& sc, float4& sh) {
    float4 s = make_float4(0.f, 0.f, 0.f, 0.f);
    float4 q = make_float4(0.f, 0.f, 0.f, 0.f);
    #pragma unroll
    for (int r = 0; r < NREP; r++) {
        const float4* p = reinterpret_cast<const float4*>(st + r * 256);
        float4 a = p[cg];          // sum part
        float4 c = p[32 + cg];     // sq part
        s.x += a.x; s.y += a.y; s.z += a.z; s.w += a.w;
        q.x += c.x; q.y += c.y; q.z += c.z; q.w += c.w;
    }
    float4 gg = reinterpret_cast<const float4*>(g)[cg];
    float4 bb = reinterpret_cast<const float4*>(b)[cg];
    bn_coef(s.x, q.x, gg.x, bb.x, sc.x, sh.x);
    bn_coef(s.y, q.y, gg.y, bb.y, sc.y, sh.y);
    bn_coef(s.z, q.z, gg.z, bb.z, sc.z, sh.z);
    bn_coef(s.w, q.w, gg.w, bb.w, sc.w, sh.w);
}

// ---------------- W transpose + bf16 convert (once per launch, all 6 weights) ----
__global__ __launch_bounds__(256) void wt_kernel(
    const float* __restrict__ W1, const float* __restrict__ W2,
    unsigned short* __restrict__ wtg)
{
    int tid = blockIdx.x * 256 + threadIdx.x;          // 6*16384 total
    if (tid >= 6 * DIM * DIM) return;
    int m = tid >> 14;           // /16384
    int r = tid & 16383;
    int c = r >> 7;              // output row (col of W)
    int k = r & 127;             // output col (row of W)
    const float* src = (m < 3) ? (W1 + (size_t)m * DIM * DIM)
                               : (W2 + (size_t)(m - 3) * DIM * DIM);
    wtg[tid] = f2bf(src[k * DIM + c]);
}

// ---------------- h0 fp32 -> bf16 (layer 0 only) ----------------
__global__ __launch_bounds__(256) void conv0_kernel(
    const float* __restrict__ h, unsigned short* __restrict__ hbf)
{
    int idx = blockIdx.x * 256 + threadIdx.x;          // per 8 elems
    if (idx >= N_NODES * D8) return;
    const float4* h4 = reinterpret_cast<const float4*>(h);
    float4 a = h4[idx * 2], b = h4[idx * 2 + 1];
    uint4 p;
    p.x = pack2(a.x, a.y); p.y = pack2(a.z, a.w);
    p.z = pack2(b.x, b.y); p.w = pack2(b.z, b.w);
    reinterpret_cast<uint4*>(hbf)[idx] = p;
}

// ---- A: per-chunk bucket histogram -> matA[c][b] (coalesced) ----
__global__ __launch_bounds__(256) void binhist_kernel(
    const int* __restrict__ dst, int* __restrict__ matA)
{
    __shared__ int lh[NBUCK];
    int t = threadIdx.x, c = blockIdx.x;
    for (int b = t; b < NBUCK; b += 256) lh[b] = 0;
    __syncthreads();
    int base = c * CHUNK;
    #pragma unroll
    for (int i = 0; i < EPT; i++) {
        int e = base + i * 256 + t;
        if (e < N_EDGES) atomicAdd(&lh[dst[e] >> BUCK_SH], 1);
    }
    __syncthreads();
    for (int b = t; b < NBUCK; b += 256) matA[c * NBUCK + b] = lh[b];
}

// ---- B: per-bucket column scan over chunks -> matoffT[b][c], btot[b] ----
__global__ __launch_bounds__(256) void colscan_kernel(
    const int* __restrict__ matA, int* __restrict__ matoffT, int* __restrict__ btot)
{
    __shared__ int s[256];
    int t = threadIdx.x, b = blockIdx.x;
    int v = (t < NCHUNK) ? matA[t * NBUCK + b] : 0;
    s[t] = v;
    __syncthreads();
    #pragma unroll
    for (int off = 1; off < 256; off <<= 1) {
        int u = (t >= off) ? s[t - off] : 0;
        __syncthreads();
        s[t] += u;
        __syncthreads();
    }
    if (t < NCHUNK) matoffT[b * NCHUNK + t] = s[t] - v;   // exclusive
    if (t == 255) btot[b] = s[255];
}

// ---- C: scan bucket totals -> bbase[b] ----
__global__ __launch_bounds__(512) void bucketbase_kernel(
    const int* __restrict__ btot, int* __restrict__ bbase)
{
    __shared__ int s[512];
    int t = threadIdx.x;
    int v = (t < NBUCK) ? btot[t] : 0;
    s[t] = v;
    __syncthreads();
    #pragma unroll
    for (int off = 1; off < 512; off <<= 1) {
        int u = (t >= off) ? s[t - off] : 0;
        __syncthreads();
        s[t] += u;
        __syncthreads();
    }
    if (t < NBUCK) bbase[t] = s[t] - v;                   // exclusive
}

// ---- D: deterministic binned fill. record = (src<<16|fp16(w), dst&127) ----
// Writes land in contiguous per-(chunk,bucket) runs (no global atomics).
__global__ __launch_bounds__(256) void binfill_kernel(
    const int* __restrict__ src, const int* __restrict__ dst,
    const float* __restrict__ ew, const int* __restrict__ matoffT,
    const int* __restrict__ bbase, uint2* __restrict__ erec)
{
    __shared__ int lh[NBUCK];
    __shared__ int loff[NBUCK];
    int t = threadIdx.x, c = blockIdx.x;
    for (int b = t; b < NBUCK; b += 256) {
        lh[b] = 0;
        loff[b] = bbase[b] + matoffT[b * NCHUNK + c];
    }
    __syncthreads();
    int base = c * CHUNK;
    #pragma unroll
    for (int i = 0; i < EPT; i++) {
        int e = base + i * 256 + t;
        if (e < N_EDGES) {
            int d = dst[e];
            int b = d >> BUCK_SH;
            int lp = atomicAdd(&lh[b], 1);
            erec[loff[b] + lp] = make_uint2(
                ((unsigned int)src[e] << 16) | (unsigned int)f2h(ew[e]),
                (unsigned int)(d & (BUCK_N - 1)));
        }
    }
}

// ---- E: bucket aggregation, 8 waves + 8-deep prefetch, split-pair LDS layout ----
// acc logical col 2c -> [dl*128 + c], col 2c+1 -> [dl*128 + 64 + c]  (bank = c%32, 2-way)
__global__ __launch_bounds__(AGG_T) void aggb_kernel(
    const unsigned int* __restrict__ h_u, const uint2* __restrict__ erec,
    const int* __restrict__ bbase, const int* __restrict__ btot,
    unsigned int* __restrict__ r_u)
{
    __shared__ float acc[BUCK_N * DIM];   // 64 KB
    int t = threadIdx.x, b = blockIdx.x;
    int node0 = b * BUCK_N;
    // init: self term (eps = 0)
    for (int id = t; id < BUCK_N * 64; id += AGG_T) {
        int r = id >> 6, cu = id & 63;
        float f0 = 0.f, f1 = 0.f;
        if (node0 + r < N_NODES) {
            unsigned int u = h_u[(size_t)(node0 + r) * 64 + cu];
            f0 = __uint_as_float(u << 16);
            f1 = __uint_as_float(u & 0xFFFF0000u);
        }
        acc[r * DIM + cu]      = f0;
        acc[r * DIM + 64 + cu] = f1;
    }
    __syncthreads();
    int beg = bbase[b], end = beg + btot[b];
    int wv = t >> 6, ln = t & 63;
    for (int j0 = beg + wv * AGG_U; j0 < end; j0 += 8 * AGG_U) {
        unsigned int rx[AGG_U]; int dl[AGG_U]; unsigned int hu[AGG_U];
        #pragma unroll
        for (int k = 0; k < AGG_U; k++) {
            int j = j0 + k;
            uint2 rec = (j < end) ? erec[j] : make_uint2(0u, 0u);
            rx[k] = (j < end) ? rec.x : 0u;     // w = fp16(0) for tail
            dl[k] = (int)rec.y;
        }
        #pragma unroll
        for (int k = 0; k < AGG_U; k++)
            hu[k] = h_u[(size_t)(rx[k] >> 16) * 64 + ln];
        #pragma unroll
        for (int k = 0; k < AGG_U; k++) {
            float w = h2f((unsigned short)(rx[k] & 0xFFFFu));
            atomicAdd(&acc[dl[k] * DIM + ln],      w * __uint_as_float(hu[k] << 16));
            atomicAdd(&acc[dl[k] * DIM + 64 + ln], w * __uint_as_float(hu[k] & 0xFFFF0000u));
        }
    }
    __syncthreads();
    for (int id = t; id < BUCK_N * 64; id += AGG_T) {
        int r = id >> 6, cu = id & 63;
        if (node0 + r < N_NODES)
            r_u[(size_t)(node0 + r) * 64 + cu] =
                pack2(acc[r * DIM + cu], acc[r * DIM + 64 + cu]);
    }
}

// ---------------- MFMA GEMM: out = f(in) @ W + bias, + column stats ----------------
// MODE 0: in = rbf (pre-staged bf16)     (GEMM1)
// MODE 1: in = relu(BN(A; st,g,b))       (GEMM2: BN1+ReLU fused on staging)
template<int MODE>
__global__ __launch_bounds__(256) void gemm_kernel(
    const unsigned short* __restrict__ Abf, const float* __restrict__ A,
    const float* __restrict__ st_in, const float* __restrict__ bn_g,
    const float* __restrict__ bn_b,
    const unsigned short* __restrict__ Wt, const float* __restrict__ bias,
    float* __restrict__ out, float* __restrict__ st_out)
{
    __shared__ unsigned short A_sm[64 * DIM];    // 16 KB bf16, XOR-swizzled
    __shared__ unsigned short W_sm[DIM * DIM];   // 32 KB bf16 W^T, XOR-swizzled
    __shared__ float2 scsh[DIM];                 // BN coefs (MODE 1)

    const int t = threadIdx.x;
    const int row0 = blockIdx.x * 64;

    if (MODE == 1) {
        if (t < 128) {
            float ssum = 0.f, ssq = 0.f;
            #pragma unroll
            for (int r = 0; r < NREP; r++) {
                ssum += st_in[r * 256 + t];
                ssq  += st_in[r * 256 + 128 + t];
            }
            float sc, sh;
            bn_coef(ssum, ssq, bn_g[t], bn_b[t], sc, sh);
            scsh[t] = make_float2(sc, sh);
        }
        __syncthreads();
    }

    // ---- stage W^T (already bf16, c-major): 2048 16B chunks ----
    {
        const uint4* wsrc = reinterpret_cast<const uint4*>(Wt);
        #pragma unroll
        for (int j = 0; j < 8; j++) {
            int id = t + j * 256;            // 0..2047
            int c  = id >> 4;
            int kc = id & 15;
            int sidx = (c * DIM + kc * 8) ^ ((c & 7) << 3);
            *reinterpret_cast<uint4*>(&W_sm[sidx]) = wsrc[id];
        }
    }

    // ---- stage A tile (swizzled) ----
    if (MODE == 0) {
        const uint4* asrc = reinterpret_cast<const uint4*>(Abf);
        #pragma unroll
        for (int j = 0; j < 4; j++) {
            int id = t + j * 256;            // 0..1023
            int r  = id >> 4;                // tile row 0..63
            int kc = id & 15;
            int row = row0 + r;
            uint4 u = make_uint4(0u, 0u, 0u, 0u);
            if (row < N_NODES) u = asrc[row * D8 + kc];
            int sidx = (r * DIM + kc * 8) ^ ((r & 7) << 3);
            *reinterpret_cast<uint4*>(&A_sm[sidx]) = u;
        }
    } else {
        const float4* A4 = reinterpret_cast<const float4*>(A);
        #pragma unroll
        for (int j = 0; j < 8; j++) {
            int id = t + j * 256;            // 0..2047
            int r  = id >> 5;                // tile row 0..63
            int q  = id & 31;                // float4 col group
            int row = row0 + r;
            float4 v = make_float4(0.f, 0.f, 0.f, 0.f);
            if (row < N_NODES) {
                float4 a = A4[(size_t)row * 32 + q];
                float2 c0 = scsh[q * 4 + 0], c1 = scsh[q * 4 + 1];
                float2 c2 = scsh[q * 4 + 2], c3 = scsh[q * 4 + 3];
                v.x = fmaxf(fmaf(a.x, c0.x, c0.y), 0.f);
                v.y = fmaxf(fmaf(a.y, c1.x, c1.y), 0.f);
                v.z = fmaxf(fmaf(a.z, c2.x, c2.y), 0.f);
                v.w = fmaxf(fmaf(a.w, c3.x, c3.y), 0.f);
            }
            ushort4 u = make_ushort4(f2bf(v.x), f2bf(v.y), f2bf(v.z), f2bf(v.w));
            int sidx = (r * DIM + q * 4) ^ ((r & 7) << 3);
            *reinterpret_cast<ushort4*>(&A_sm[sidx]) = u;
        }
    }
    __syncthreads();

    // ---- MFMA: wave w owns rows w*16..w*16+15, all 8 col-blocks ----
    const int w    = t >> 6;
    const int lane = t & 63;
    const int lrow = lane & 15;
    const int lkg  = lane >> 4;
    const int arow = w * 16 + lrow;

    bf16x8 afr[4];
    #pragma unroll
    for (int ks = 0; ks < 4; ks++) {
        int k = ks * 32 + lkg * 8;
        int idx = (arow * DIM + k) ^ ((arow & 7) << 3);
        afr[ks] = *reinterpret_cast<const bf16x8*>(&A_sm[idx]);
    }

    f32x4 acc[8];
    #pragma unroll
    for (int cb = 0; cb < 8; cb++) {
        f32x4 a = {0.f, 0.f, 0.f, 0.f};
        int col = cb * 16 + lrow;
        #pragma unroll
        for (int ks = 0; ks < 4; ks++) {
            int k = ks * 32 + lkg * 8;
            int widx = (col * DIM + k) ^ ((col & 7) << 3);
            bf16x8 bfr = *reinterpret_cast<const bf16x8*>(&W_sm[widx]);
            a = __builtin_amdgcn_mfma_f32_16x16x32_bf16(afr[ks], bfr, a, 0, 0, 0);
        }
        acc[cb] = a;
    }

    // ---- epilogue: bias add, store, column stats ----
    float s_c[8], q_c[8];
    #pragma unroll
    for (int cb = 0; cb < 8; cb++) {
        int col = cb * 16 + lrow;
        float bc = bias[col];
        float s = 0.f, q = 0.f;
        #pragma unroll
        for (int r = 0; r < 4; r++) {
            int row = row0 + w * 16 + lkg * 4 + r;
            if (row < N_NODES) {
                float v = acc[cb][r] + bc;
                out[(size_t)row * DIM + col] = v;
                s += v; q += v * v;
            }
        }
        s_c[cb] = s; q_c[cb] = q;
    }
    #pragma unroll
    for (int cb = 0; cb < 8; cb++) {
        s_c[cb] += __shfl_xor(s_c[cb], 16); s_c[cb] += __shfl_xor(s_c[cb], 32);
        q_c[cb] += __shfl_xor(q_c[cb], 16); q_c[cb] += __shfl_xor(q_c[cb], 32);
    }
    __syncthreads();                 // done with A_sm, reuse as reduce scratch
    float* red = reinterpret_cast<float*>(A_sm);   // [4 waves][2][128]
    if (lkg == 0) {
        #pragma unroll
        for (int cb = 0; cb < 8; cb++) {
            red[w * 256 + cb * 16 + lrow]       = s_c[cb];
            red[w * 256 + 128 + cb * 16 + lrow] = q_c[cb];
        }
    }
    __syncthreads();
    float* strep = st_out + (blockIdx.x & (NREP - 1)) * 256;
    if (t < 256) {
        float v = red[t] + red[256 + t] + red[512 + t] + red[768 + t];
        unsafeAtomicAdd(&strep[t], v);
    }
}

// ---------------- stats of xa = relu(BN(x; stA)) — no data write ----------------
__global__ __launch_bounds__(256) void bn_stats_kernel(
    const float* __restrict__ x, const float* __restrict__ st_in,
    const float* __restrict__ bn_g, const float* __restrict__ bn_b,
    float* __restrict__ st_out)
{
    const int t = threadIdx.x;
    const int cg = t & 31;
    float4 sc, sh;
    bn_coef4(st_in, bn_g, bn_b, cg, sc, sh);
    const float4* x4 = reinterpret_cast<const float4*>(x);
    float4 psum = make_float4(0.f, 0.f, 0.f, 0.f);
    float4 psq  = make_float4(0.f, 0.f, 0.f, 0.f);
    const int total = N_NODES * 32;
    const int stride = gridDim.x * 256;
    for (int idx = blockIdx.x * 256 + t; idx < total; idx += stride) {
        float4 v = x4[idx];
        v.x = fmaxf(fmaf(v.x, sc.x, sh.x), 0.f);
        v.y = fmaxf(fmaf(v.y, sc.y, sh.y), 0.f);
        v.z = fmaxf(fmaf(v.z, sc.z, sh.z), 0.f);
        v.w = fmaxf(fmaf(v.w, sc.w, sh.w), 0.f);
        psum.x += v.x; psum.y += v.y; psum.z += v.z; psum.w += v.w;
        psq.x += v.x * v.x; psq.y += v.y * v.y; psq.z += v.z * v.z; psq.w += v.w * v.w;
    }
    __shared__ float4 red[512];
    red[t]       = psum;
    red[256 + t] = psq;
    __syncthreads();
    if (t < 32) {
        float4 s = make_float4(0.f, 0.f, 0.f, 0.f);
        float4 q = make_float4(0.f, 0.f, 0.f, 0.f);
        #pragma unroll
        for (int r = 0; r < 8; r++) {
            float4 a = red[r * 32 + t];
            float4 b = red[256 + r * 32 + t];
            s.x += a.x; s.y += a.y; s.z += a.z; s.w += a.w;
            q.x += b.x; q.y += b.y; q.z += b.z; q.w += b.w;
        }
        float* strep = st_out + (blockIdx.x & (NREP - 1)) * 256;
        float* gs = strep + t * 4;
        float* gq = strep + 128 + t * 4;
        unsafeAtomicAdd(gs + 0, s.x); unsafeAtomicAdd(gs + 1, s.y);
        unsafeAtomicAdd(gs + 2, s.z); unsafeAtomicAdd(gs + 3, s.w);
        unsafeAtomicAdd(gq + 0, q.x); unsafeAtomicAdd(gq + 1, q.y);
        unsafeAtomicAdd(gq + 2, q.z); unsafeAtomicAdd(gq + 3, q.w);
    }
}

// ---------------- h = relu(BN_o(relu(BN_a(x)))) ----------------
// LAST=0: write bf16 h only (next layer input). LAST=1: write fp32 d_out only.
template<int LAST>
__global__ __launch_bounds__(256) void bn_final_kernel(
    const float* __restrict__ x,
    const float* __restrict__ stA, const float* __restrict__ ga, const float* __restrict__ ba,
    const float* __restrict__ stO, const float* __restrict__ go, const float* __restrict__ bo,
    float* __restrict__ y, unsigned short* __restrict__ ybf)
{
    const int t = threadIdx.x;
    const int cg = t & 31;
    float4 sca, sha, sco, sho;
    bn_coef4(stA, ga, ba, cg, sca, sha);
    bn_coef4(stO, go, bo, cg, sco, sho);
    const float4* x4 = reinterpret_cast<const float4*>(x);
    float4* y4 = reinterpret_cast<float4*>(y);
    const int total = N_NODES * 32;
    const int stride = gridDim.x * 256;
    for (int idx = blockIdx.x * 256 + t; idx < total; idx += stride) {
        float4 v = x4[idx];
        v.x = fmaxf(fmaf(v.x, sca.x, sha.x), 0.f);
        v.y = fmaxf(fmaf(v.y, sca.y, sha.y), 0.f);
        v.z = fmaxf(fmaf(v.z, sca.z, sha.z), 0.f);
        v.w = fmaxf(fmaf(v.w, sca.w, sha.w), 0.f);
        v.x = fmaxf(fmaf(v.x, sco.x, sho.x), 0.f);
        v.y = fmaxf(fmaf(v.y, sco.y, sho.y), 0.f);
        v.z = fmaxf(fmaf(v.z, sco.z, sho.z), 0.f);
        v.w = fmaxf(fmaf(v.w, sco.w, sho.w), 0.f);
        if (LAST) {
            y4[idx] = v;
        } else {
            ushort4 u = make_ushort4(f2bf(v.x), f2bf(v.y), f2bf(v.z), f2bf(v.w));
            reinterpret_cast<ushort4*>(ybf)[idx] = u;
        }
    }
}

extern "C" void kernel_launch(void* const* d_in, const int* in_sizes, int n_in,
                              void* d_out, int out_size, void* d_ws, size_t ws_size,
                              hipStream_t stream)
{
    const float* h0    = (const float*)d_in[0];
    const int*   src   = (const int*)d_in[1];
    const int*   dst   = (const int*)d_in[2];
    const float* ew    = (const float*)d_in[3];
    const float* W1    = (const float*)d_in[4];
    const float* b1    = (const float*)d_in[5];
    const float* bn1_g = (const float*)d_in[6];
    const float* bn1_b = (const float*)d_in[7];
    const float* W2    = (const float*)d_in[8];
    const float* b2    = (const float*)d_in[9];
    const float* bna_g = (const float*)d_in[10];
    const float* bna_b = (const float*)d_in[11];
    const float* bno_g = (const float*)d_in[12];
    const float* bno_b = (const float*)d_in[13];

    const size_t ND = (size_t)N_NODES * DIM;
    float* R0      = (float*)d_ws;                        // N*D floats
    float* R1      = R0 + ND;                             // N*D floats
    float* stats   = R1 + ND;                             // 9 * STSZ floats
    int*   matA    = (int*)(stats + 9 * STSZ);            // NCHUNK*NBUCK
    int*   matoffT = matA + NCHUNK * NBUCK;               // NBUCK*NCHUNK
    int*   btot    = matoffT + NBUCK * NCHUNK;            // NBUCK
    int*   bbase   = btot + NBUCK;                        // NBUCK
    uint2* erec    = (uint2*)(((uintptr_t)(bbase + NBUCK) + 15) & ~(uintptr_t)15); // E uint2
    unsigned short* wtg = (unsigned short*)(erec + N_EDGES);   // 6*128*128 bf16
    float* hout    = (float*)d_out;

    hipMemsetAsync(stats, 0, 9 * STSZ * sizeof(float), stream);
    wt_kernel<<<(6 * DIM * DIM + 255) / 256, 256, 0, stream>>>(W1, W2, wtg);
    conv0_kernel<<<(N_NODES * D8 + 255) / 256, 256, 0, stream>>>(h0, (unsigned short*)R0);

    const int gemm_grid = (N_NODES + 63) / 64;            // 782

    for (int i = 0; i < N_LAYERS; i++) {
        const int* srcL = src + (size_t)i * N_EDGES;
        const int* dstL = dst + (size_t)i * N_EDGES;
        const float* ewL = ew + (size_t)i * N_EDGES;
        float* st1 = stats + (size_t)(i * 3 + 0) * STSZ;  // NREP x [sum(128)|sq(128)]
        float* stA = stats + (size_t)(i * 3 + 1) * STSZ;
        float* stO = stats + (size_t)(i * 3 + 2) * STSZ;
        const unsigned short* wt1 = wtg + (size_t)i * DIM * DIM;
        const unsigned short* wt2 = wtg + (size_t)(i + 3) * DIM * DIM;

        // ping-pong regions: even layers h/r in R0, odd layers in R1
        float* Re = (i & 1) ? R1 : R0;
        float* Ro = (i & 1) ? R0 : R1;
        unsigned short* hbf = (unsigned short*)Re;        // first half of Re
        unsigned short* rbf = (unsigned short*)Re + ND;   // second half of Re
        float* x1 = Ro;
        float* x2 = Re;                                   // clobbers hbf+rbf (dead)
        unsigned short* ybf = (unsigned short*)Ro;        // next layer's hbf

        // --- deterministic binned CSR-lite + bucket aggregation ---
        binhist_kernel<<<NCHUNK, 256, 0, stream>>>(dstL, matA);
        colscan_kernel<<<NBUCK, 256, 0, stream>>>(matA, matoffT, btot);
        bucketbase_kernel<<<1, 512, 0, stream>>>(btot, bbase);
        binfill_kernel<<<NCHUNK, 256, 0, stream>>>(srcL, dstL, ewL, matoffT, bbase, erec);
        aggb_kernel<<<NBUCK, AGG_T, 0, stream>>>(
            (const unsigned int*)hbf, erec, bbase, btot, (unsigned int*)rbf);

        gemm_kernel<0><<<gemm_grid, 256, 0, stream>>>(
            rbf, nullptr, nullptr, nullptr, nullptr,
            wt1, b1 + (size_t)i * DIM, x1, st1);

        gemm_kernel<1><<<gemm_grid, 256, 0, stream>>>(
            nullptr, x1, st1, bn1_g + (size_t)i * DIM, bn1_b + (size_t)i * DIM,
            wt2, b2 + (size_t)i * DIM, x2, stA);

        bn_stats_kernel<<<1024, 256, 0, stream>>>(
            x2, stA, bna_g + (size_t)i * DIM, bna_b + (size_t)i * DIM, stO);

        if (i == N_LAYERS - 1) {
            bn_final_kernel<1><<<1024, 256, 0, stream>>>(
                x2, stA, bna_g + (size_t)i * DIM, bna_b + (size_t)i * DIM,
                stO, bno_g + (size_t)i * DIM, bno_b + (size_t)i * DIM, hout, nullptr);
        } else {
            bn_final_kernel<0><<<1024, 256, 0, stream>>>(
                x2, stA, bna_g + (size_t)i * DIM, bna_b + (size_t)i * DIM,
                stO, bno_g + (size_t)i * DIM, bno_b + (size_t)i * DIM, nullptr, ybf);
        }
    }
}

// Round 14
// 570.283 us; speedup vs baseline: 4.4303x; 4.4238x over previous
//
#include <hip/hip_runtime.h>

#define N_NODES 50000
#define DIM 128
#define D8 16            // DIM/8 (uint4 = 8 bf16 chunks per row)
#define N_EDGES 800000
#define N_LAYERS 3
#define BN_EPS 1e-5f
#define NREP 16                              // stat replicas (atomic-chain breaker)
#define STSZ (256 * NREP)                    // floats per stat set
#define CHUNK 4096
#define NCHUNK ((N_EDGES + CHUNK - 1) / CHUNK)   // 196
#define EPT (CHUNK / 256)                        // 16
#define BUCK_SH 7
#define BUCK_N 128
#define NBUCK ((N_NODES + BUCK_N - 1) / BUCK_N)  // 391

typedef __attribute__((ext_vector_type(8))) short bf16x8;
typedef __attribute__((ext_vector_type(4))) float f32x4;

// fp32 -> bf16 round-to-nearest-even
__device__ __forceinline__ unsigned short f2bf(float f) {
    unsigned int u = __float_as_uint(f);
    u = (u + 0x7FFFu + ((u >> 16) & 1u)) >> 16;
    return (unsigned short)u;
}
__device__ __forceinline__ unsigned int pack2(float a, float b) {
    return (unsigned int)f2bf(a) | ((unsigned int)f2bf(b) << 16);
}
// fp32 <-> fp16 (RTE via native cast)
__device__ __forceinline__ unsigned short f2h(float f) {
    _Float16 h = (_Float16)f;
    unsigned short u;
    __builtin_memcpy(&u, &h, 2);
    return u;
}
__device__ __forceinline__ float h2f(unsigned short u) {
    _Float16 h;
    __builtin_memcpy(&h, &u, 2);
    return (float)h;
}
__device__ __forceinline__ void bf8_fma(uint4 u, float w, float* acc) {
    acc[0] = fmaf(w, __uint_as_float(u.x << 16), acc[0]);
    acc[1] = fmaf(w, __uint_as_float(u.x & 0xFFFF0000u), acc[1]);
    acc[2] = fmaf(w, __uint_as_float(u.y << 16), acc[2]);
    acc[3] = fmaf(w, __uint_as_float(u.y & 0xFFFF0000u), acc[3]);
    acc[4] = fmaf(w, __uint_as_float(u.z << 16), acc[4]);
    acc[5] = fmaf(w, __uint_as_float(u.z & 0xFFFF0000u), acc[5]);
    acc[6] = fmaf(w, __uint_as_float(u.w << 16), acc[6]);
    acc[7] = fmaf(w, __uint_as_float(u.w & 0xFFFF0000u), acc[7]);
}

// scale/shift from raw BN stats
__device__ __forceinline__ void bn_coef(float sum, float sq, float g, float b,
                                        float& sc, float& sh) {
    float mean = sum * (1.f / N_NODES);
    float var  = sq * (1.f / N_NODES) - mean * mean;
    float rstd = rsqrtf(var + BN_EPS);
    sc = g * rstd;
    sh = b - mean * sc;
}

// sum NREP replicas, then coefs (vector form; cg = float4 column group)
__device__ __forceinline__ void bn_coef4(const float* st,
                                         const float* g, const float* b, int cg,
                                         float4& sc, float4& sh) {
    float4 s = make_float4(0.f, 0.f, 0.f, 0.f);
    float4 q = make_float4(0.f, 0.f, 0.f, 0.f);
    #pragma unroll
    for (int r = 0; r < NREP; r++) {
        const float4* p = reinterpret_cast<const float4*>(st + r * 256);
        float4 a = p[cg];          // sum part
        float4 c = p[32 + cg];     // sq part
        s.x += a.x; s.y += a.y; s.z += a.z; s.w += a.w;
        q.x += c.x; q.y += c.y; q.z += c.z; q.w += c.w;
    }
    float4 gg = reinterpret_cast<const float4*>(g)[cg];
    float4 bb = reinterpret_cast<const float4*>(b)[cg];
    bn_coef(s.x, q.x, gg.x, bb.x, sc.x, sh.x);
    bn_coef(s.y, q.y, gg.y, bb.y, sc.y, sh.y);
    bn_coef(s.z, q.z, gg.z, bb.z, sc.z, sh.z);
    bn_coef(s.w, q.w, gg.w, bb.w, sc.w, sh.w);
}

// ---------------- W transpose + bf16 convert (once per launch, all 6 weights) ----
__global__ __launch_bounds__(256) void wt_kernel(
    const float* __restrict__ W1, const float* __restrict__ W2,
    unsigned short* __restrict__ wtg)
{
    int tid = blockIdx.x * 256 + threadIdx.x;          // 6*16384 total
    if (tid >= 6 * DIM * DIM) return;
    int m = tid >> 14;           // /16384
    int r = tid & 16383;
    int c = r >> 7;              // output row (col of W)
    int k = r & 127;             // output col (row of W)
    const float* src = (m < 3) ? (W1 + (size_t)m * DIM * DIM)
                               : (W2 + (size_t)(m - 3) * DIM * DIM);
    wtg[tid] = f2bf(src[k * DIM + c]);
}

// ---------------- h0 fp32 -> bf16 (layer 0 only) ----------------
__global__ __launch_bounds__(256) void conv0_kernel(
    const float* __restrict__ h, unsigned short* __restrict__ hbf)
{
    int idx = blockIdx.x * 256 + threadIdx.x;          // per 8 elems
    if (idx >= N_NODES * D8) return;
    const float4* h4 = reinterpret_cast<const float4*>(h);
    float4 a = h4[idx * 2], b = h4[idx * 2 + 1];
    uint4 p;
    p.x = pack2(a.x, a.y); p.y = pack2(a.z, a.w);
    p.z = pack2(b.x, b.y); p.w = pack2(b.z, b.w);
    reinterpret_cast<uint4*>(hbf)[idx] = p;
}

// ---- A: per-chunk bucket histogram -> matA[c][b] (coalesced, int LDS atomics) ----
__global__ __launch_bounds__(256) void binhist_kernel(
    const int* __restrict__ dst, int* __restrict__ matA)
{
    __shared__ int lh[NBUCK];
    int t = threadIdx.x, c = blockIdx.x;
    for (int b = t; b < NBUCK; b += 256) lh[b] = 0;
    __syncthreads();
    int base = c * CHUNK;
    #pragma unroll
    for (int i = 0; i < EPT; i++) {
        int e = base + i * 256 + t;
        if (e < N_EDGES) atomicAdd(&lh[dst[e] >> BUCK_SH], 1);
    }
    __syncthreads();
    for (int b = t; b < NBUCK; b += 256) matA[c * NBUCK + b] = lh[b];
}

// ---- B: per-bucket column scan over chunks -> matoffT[b][c], btot[b] ----
__global__ __launch_bounds__(256) void colscan_kernel(
    const int* __restrict__ matA, int* __restrict__ matoffT, int* __restrict__ btot)
{
    __shared__ int s[256];
    int t = threadIdx.x, b = blockIdx.x;
    int v = (t < NCHUNK) ? matA[t * NBUCK + b] : 0;
    s[t] = v;
    __syncthreads();
    #pragma unroll
    for (int off = 1; off < 256; off <<= 1) {
        int u = (t >= off) ? s[t - off] : 0;
        __syncthreads();
        s[t] += u;
        __syncthreads();
    }
    if (t < NCHUNK) matoffT[b * NCHUNK + t] = s[t] - v;   // exclusive
    if (t == 255) btot[b] = s[255];
}

// ---- C: scan bucket totals -> bbase[b] ----
__global__ __launch_bounds__(512) void bucketbase_kernel(
    const int* __restrict__ btot, int* __restrict__ bbase)
{
    __shared__ int s[512];
    int t = threadIdx.x;
    int v = (t < NBUCK) ? btot[t] : 0;
    s[t] = v;
    __syncthreads();
    #pragma unroll
    for (int off = 1; off < 512; off <<= 1) {
        int u = (t >= off) ? s[t - off] : 0;
        __syncthreads();
        s[t] += u;
        __syncthreads();
    }
    if (t < NBUCK) bbase[t] = s[t] - v;                   // exclusive
}

// ---- D: deterministic binned fill. record = (src<<16|fp16(w), dst&127) ----
// Writes land in contiguous per-(chunk,bucket) runs (no global atomics).
__global__ __launch_bounds__(256) void binfill_kernel(
    const int* __restrict__ src, const int* __restrict__ dst,
    const float* __restrict__ ew, const int* __restrict__ matoffT,
    const int* __restrict__ bbase, uint2* __restrict__ erec)
{
    __shared__ int lh[NBUCK];
    __shared__ int loff[NBUCK];
    int t = threadIdx.x, c = blockIdx.x;
    for (int b = t; b < NBUCK; b += 256) {
        lh[b] = 0;
        loff[b] = bbase[b] + matoffT[b * NCHUNK + c];
    }
    __syncthreads();
    int base = c * CHUNK;
    #pragma unroll
    for (int i = 0; i < EPT; i++) {
        int e = base + i * 256 + t;
        if (e < N_EDGES) {
            int d = dst[e];
            int b = d >> BUCK_SH;
            int lp = atomicAdd(&lh[b], 1);
            erec[loff[b] + lp] = make_uint2(
                ((unsigned int)src[e] << 16) | (unsigned int)f2h(ew[e]),
                (unsigned int)(d & (BUCK_N - 1)));
        }
    }
}

// ---- D2: per-bucket counting sort to node order; emits CSR offs + 4B records ----
// One block per bucket. Records stay in the bucket's contiguous (L2-hot) region.
__global__ __launch_bounds__(256) void sortbucket_kernel(
    const uint2* __restrict__ erec, const int* __restrict__ bbase,
    const int* __restrict__ btot, unsigned int* __restrict__ erec2,
    int* __restrict__ offs)
{
    __shared__ int lh[BUCK_N];    // hist -> exclusive scan -> cursor
    __shared__ int ls[BUCK_N];    // scan scratch
    int t = threadIdx.x, b = blockIdx.x;
    int beg = bbase[b], cnt = btot[b];
    int node0 = b * BUCK_N;
    if (t < BUCK_N) lh[t] = 0;
    __syncthreads();
    for (int j = t; j < cnt; j += 256)
        atomicAdd(&lh[(int)erec[beg + j].y], 1);
    __syncthreads();
    // exclusive scan of lh[0..127]
    int v = (t < BUCK_N) ? lh[t] : 0;
    if (t < BUCK_N) ls[t] = v;
    __syncthreads();
    #pragma unroll
    for (int off = 1; off < BUCK_N; off <<= 1) {
        int u = (t < BUCK_N && t >= off) ? ls[t - off] : 0;
        __syncthreads();
        if (t < BUCK_N) ls[t] += u;
        __syncthreads();
    }
    if (t < BUCK_N) {
        int ex = ls[t] - v;
        lh[t] = ex;                               // cursor = exclusive prefix
        if (node0 + t < N_NODES) offs[node0 + t] = beg + ex;
    }
    if (b == 0 && t == 0) offs[N_NODES] = N_EDGES;
    __syncthreads();
    for (int j = t; j < cnt; j += 256) {
        uint2 rec = erec[beg + j];
        int p = atomicAdd(&lh[(int)rec.y], 1);
        erec2[beg + p] = rec.x;
    }
}

// ---- E: per-node gather aggregation (16 lanes/node, register accum, NO atomics) ----
// rbf[n] = bf16( h[n] + sum_{e: dst=n} w_e * h[src_e] )
__global__ __launch_bounds__(256) void agg_kernel(
    const unsigned short* __restrict__ hbf, const int* __restrict__ offs,
    const unsigned int* __restrict__ erec2, unsigned short* __restrict__ rbf)
{
    int gid = blockIdx.x * 256 + threadIdx.x;
    int node = gid >> 4;
    if (node >= N_NODES) return;
    int lane = gid & 15;
    const uint4* h4 = reinterpret_cast<const uint4*>(hbf);
    int cidx = node * D8 + lane;
    float acc[8] = {0.f, 0.f, 0.f, 0.f, 0.f, 0.f, 0.f, 0.f};
    bf8_fma(h4[cidx], 1.0f, acc);                 // self term (eps = 0)
    int beg = offs[node], end = offs[node + 1];
    for (int j = beg; j < end; j++) {
        unsigned int rec = erec2[j];
        float w = h2f((unsigned short)(rec & 0xFFFFu));
        bf8_fma(h4[(rec >> 16) * D8 + lane], w, acc);
    }
    uint4 p;
    p.x = pack2(acc[0], acc[1]); p.y = pack2(acc[2], acc[3]);
    p.z = pack2(acc[4], acc[5]); p.w = pack2(acc[6], acc[7]);
    reinterpret_cast<uint4*>(rbf)[cidx] = p;
}

// ---------------- MFMA GEMM: out = f(in) @ W + bias, + column stats ----------------
// MODE 0: in = rbf (pre-staged bf16)     (GEMM1)
// MODE 1: in = relu(BN(A; st,g,b))       (GEMM2: BN1+ReLU fused on staging)
template<int MODE>
__global__ __launch_bounds__(256) void gemm_kernel(
    const unsigned short* __restrict__ Abf, const float* __restrict__ A,
    const float* __restrict__ st_in, const float* __restrict__ bn_g,
    const float* __restrict__ bn_b,
    const unsigned short* __restrict__ Wt, const float* __restrict__ bias,
    float* __restrict__ out, float* __restrict__ st_out)
{
    __shared__ unsigned short A_sm[64 * DIM];    // 16 KB bf16, XOR-swizzled
    __shared__ unsigned short W_sm[DIM * DIM];   // 32 KB bf16 W^T, XOR-swizzled
    __shared__ float2 scsh[DIM];                 // BN coefs (MODE 1)

    const int t = threadIdx.x;
    const int row0 = blockIdx.x * 64;

    if (MODE == 1) {
        if (t < 128) {
            float ssum = 0.f, ssq = 0.f;
            #pragma unroll
            for (int r = 0; r < NREP; r++) {
                ssum += st_in[r * 256 + t];
                ssq  += st_in[r * 256 + 128 + t];
            }
            float sc, sh;
            bn_coef(ssum, ssq, bn_g[t], bn_b[t], sc, sh);
            scsh[t] = make_float2(sc, sh);
        }
        __syncthreads();
    }

    // ---- stage W^T (already bf16, c-major): 2048 16B chunks ----
    {
        const uint4* wsrc = reinterpret_cast<const uint4*>(Wt);
        #pragma unroll
        for (int j = 0; j < 8; j++) {
            int id = t + j * 256;            // 0..2047
            int c  = id >> 4;
            int kc = id & 15;
            int sidx = (c * DIM + kc * 8) ^ ((c & 7) << 3);
            *reinterpret_cast<uint4*>(&W_sm[sidx]) = wsrc[id];
        }
    }

    // ---- stage A tile (swizzled) ----
    if (MODE == 0) {
        const uint4* asrc = reinterpret_cast<const uint4*>(Abf);
        #pragma unroll
        for (int j = 0; j < 4; j++) {
            int id = t + j * 256;            // 0..1023
            int r  = id >> 4;                // tile row 0..63
            int kc = id & 15;
            int row = row0 + r;
            uint4 u = make_uint4(0u, 0u, 0u, 0u);
            if (row < N_NODES) u = asrc[row * D8 + kc];
            int sidx = (r * DIM + kc * 8) ^ ((r & 7) << 3);
            *reinterpret_cast<uint4*>(&A_sm[sidx]) = u;
        }
    } else {
        const float4* A4 = reinterpret_cast<const float4*>(A);
        #pragma unroll
        for (int j = 0; j < 8; j++) {
            int id = t + j * 256;            // 0..2047
            int r  = id >> 5;                // tile row 0..63
            int q  = id & 31;                // float4 col group
            int row = row0 + r;
            float4 v = make_float4(0.f, 0.f, 0.f, 0.f);
            if (row < N_NODES) {
                float4 a = A4[(size_t)row * 32 + q];
                float2 c0 = scsh[q * 4 + 0], c1 = scsh[q * 4 + 1];
                float2 c2 = scsh[q * 4 + 2], c3 = scsh[q * 4 + 3];
                v.x = fmaxf(fmaf(a.x, c0.x, c0.y), 0.f);
                v.y = fmaxf(fmaf(a.y, c1.x, c1.y), 0.f);
                v.z = fmaxf(fmaf(a.z, c2.x, c2.y), 0.f);
                v.w = fmaxf(fmaf(a.w, c3.x, c3.y), 0.f);
            }
            ushort4 u = make_ushort4(f2bf(v.x), f2bf(v.y), f2bf(v.z), f2bf(v.w));
            int sidx = (r * DIM + q * 4) ^ ((r & 7) << 3);
            *reinterpret_cast<ushort4*>(&A_sm[sidx]) = u;
        }
    }
    __syncthreads();

    // ---- MFMA: wave w owns rows w*16..w*16+15, all 8 col-blocks ----
    const int w    = t >> 6;
    const int lane = t & 63;
    const int lrow = lane & 15;
    const int lkg  = lane >> 4;
    const int arow = w * 16 + lrow;

    bf16x8 afr[4];
    #pragma unroll
    for (int ks = 0; ks < 4; ks++) {
        int k = ks * 32 + lkg * 8;
        int idx = (arow * DIM + k) ^ ((arow & 7) << 3);
        afr[ks] = *reinterpret_cast<const bf16x8*>(&A_sm[idx]);
    }

    f32x4 acc[8];
    #pragma unroll
    for (int cb = 0; cb < 8; cb++) {
        f32x4 a = {0.f, 0.f, 0.f, 0.f};
        int col = cb * 16 + lrow;
        #pragma unroll
        for (int ks = 0; ks < 4; ks++) {
            int k = ks * 32 + lkg * 8;
            int widx = (col * DIM + k) ^ ((col & 7) << 3);
            bf16x8 bfr = *reinterpret_cast<const bf16x8*>(&W_sm[widx]);
            a = __builtin_amdgcn_mfma_f32_16x16x32_bf16(afr[ks], bfr, a, 0, 0, 0);
        }
        acc[cb] = a;
    }

    // ---- epilogue: bias add, store, column stats ----
    float s_c[8], q_c[8];
    #pragma unroll
    for (int cb = 0; cb < 8; cb++) {
        int col = cb * 16 + lrow;
        float bc = bias[col];
        float s = 0.f, q = 0.f;
        #pragma unroll
        for (int r = 0; r < 4; r++) {
            int row = row0 + w * 16 + lkg * 4 + r;
            if (row < N_NODES) {
                float v = acc[cb][r] + bc;
                out[(size_t)row * DIM + col] = v;
                s += v; q += v * v;
            }
        }
        s_c[cb] = s; q_c[cb] = q;
    }
    #pragma unroll
    for (int cb = 0; cb < 8; cb++) {
        s_c[cb] += __shfl_xor(s_c[cb], 16); s_c[cb] += __shfl_xor(s_c[cb], 32);
        q_c[cb] += __shfl_xor(q_c[cb], 16); q_c[cb] += __shfl_xor(q_c[cb], 32);
    }
    __syncthreads();                 // done with A_sm, reuse as reduce scratch
    float* red = reinterpret_cast<float*>(A_sm);   // [4 waves][2][128]
    if (lkg == 0) {
        #pragma unroll
        for (int cb = 0; cb < 8; cb++) {
            red[w * 256 + cb * 16 + lrow]       = s_c[cb];
            red[w * 256 + 128 + cb * 16 + lrow] = q_c[cb];
        }
    }
    __syncthreads();
    float* strep = st_out + (blockIdx.x & (NREP - 1)) * 256;
    if (t < 256) {
        float v = red[t] + red[256 + t] + red[512 + t] + red[768 + t];
        unsafeAtomicAdd(&strep[t], v);
    }
}

// ---------------- stats of xa = relu(BN(x; stA)) — no data write ----------------
__global__ __launch_bounds__(256) void bn_stats_kernel(
    const float* __restrict__ x, const float* __restrict__ st_in,
    const float* __restrict__ bn_g, const float* __restrict__ bn_b,
    float* __restrict__ st_out)
{
    const int t = threadIdx.x;
    const int cg = t & 31;
    float4 sc, sh;
    bn_coef4(st_in, bn_g, bn_b, cg, sc, sh);
    const float4* x4 = reinterpret_cast<const float4*>(x);
    float4 psum = make_float4(0.f, 0.f, 0.f, 0.f);
    float4 psq  = make_float4(0.f, 0.f, 0.f, 0.f);
    const int total = N_NODES * 32;
    const int stride = gridDim.x * 256;
    for (int idx = blockIdx.x * 256 + t; idx < total; idx += stride) {
        float4 v = x4[idx];
        v.x = fmaxf(fmaf(v.x, sc.x, sh.x), 0.f);
        v.y = fmaxf(fmaf(v.y, sc.y, sh.y), 0.f);
        v.z = fmaxf(fmaf(v.z, sc.z, sh.z), 0.f);
        v.w = fmaxf(fmaf(v.w, sc.w, sh.w), 0.f);
        psum.x += v.x; psum.y += v.y; psum.z += v.z; psum.w += v.w;
        psq.x += v.x * v.x; psq.y += v.y * v.y; psq.z += v.z * v.z; psq.w += v.w * v.w;
    }
    __shared__ float4 red[512];
    red[t]       = psum;
    red[256 + t] = psq;
    __syncthreads();
    if (t < 32) {
        float4 s = make_float4(0.f, 0.f, 0.f, 0.f);
        float4 q = make_float4(0.f, 0.f, 0.f, 0.f);
        #pragma unroll
        for (int r = 0; r < 8; r++) {
            float4 a = red[r * 32 + t];
            float4 b = red[256 + r * 32 + t];
            s.x += a.x; s.y += a.y; s.z += a.z; s.w += a.w;
            q.x += b.x; q.y += b.y; q.z += b.z; q.w += b.w;
        }
        float* strep = st_out + (blockIdx.x & (NREP - 1)) * 256;
        float* gs = strep + t * 4;
        float* gq = strep + 128 + t * 4;
        unsafeAtomicAdd(gs + 0, s.x); unsafeAtomicAdd(gs + 1, s.y);
        unsafeAtomicAdd(gs + 2, s.z); unsafeAtomicAdd(gs + 3, s.w);
        unsafeAtomicAdd(gq + 0, q.x); unsafeAtomicAdd(gq + 1, q.y);
        unsafeAtomicAdd(gq + 2, q.z); unsafeAtomicAdd(gq + 3, q.w);
    }
}

// ---------------- h = relu(BN_o(relu(BN_a(x)))) ----------------
// LAST=0: write bf16 h only (next layer input). LAST=1: write fp32 d_out only.
template<int LAST>
__global__ __launch_bounds__(256) void bn_final_kernel(
    const float* __restrict__ x,
    const float* __restrict__ stA, const float* __restrict__ ga, const float* __restrict__ ba,
    const float* __restrict__ stO, const float* __restrict__ go, const float* __restrict__ bo,
    float* __restrict__ y, unsigned short* __restrict__ ybf)
{
    const int t = threadIdx.x;
    const int cg = t & 31;
    float4 sca, sha, sco, sho;
    bn_coef4(stA, ga, ba, cg, sca, sha);
    bn_coef4(stO, go, bo, cg, sco, sho);
    const float4* x4 = reinterpret_cast<const float4*>(x);
    float4* y4 = reinterpret_cast<float4*>(y);
    const int total = N_NODES * 32;
    const int stride = gridDim.x * 256;
    for (int idx = blockIdx.x * 256 + t; idx < total; idx += stride) {
        float4 v = x4[idx];
        v.x = fmaxf(fmaf(v.x, sca.x, sha.x), 0.f);
        v.y = fmaxf(fmaf(v.y, sca.y, sha.y), 0.f);
        v.z = fmaxf(fmaf(v.z, sca.z, sha.z), 0.f);
        v.w = fmaxf(fmaf(v.w, sca.w, sha.w), 0.f);
        v.x = fmaxf(fmaf(v.x, sco.x, sho.x), 0.f);
        v.y = fmaxf(fmaf(v.y, sco.y, sho.y), 0.f);
        v.z = fmaxf(fmaf(v.z, sco.z, sho.z), 0.f);
        v.w = fmaxf(fmaf(v.w, sco.w, sho.w), 0.f);
        if (LAST) {
            y4[idx] = v;
        } else {
            ushort4 u = make_ushort4(f2bf(v.x), f2bf(v.y), f2bf(v.z), f2bf(v.w));
            reinterpret_cast<ushort4*>(ybf)[idx] = u;
        }
    }
}

extern "C" void kernel_launch(void* const* d_in, const int* in_sizes, int n_in,
                              void* d_out, int out_size, void* d_ws, size_t ws_size,
                              hipStream_t stream)
{
    const float* h0    = (const float*)d_in[0];
    const int*   src   = (const int*)d_in[1];
    const int*   dst   = (const int*)d_in[2];
    const float* ew    = (const float*)d_in[3];
    const float* W1    = (const float*)d_in[4];
    const float* b1    = (const float*)d_in[5];
    const float* bn1_g = (const float*)d_in[6];
    const float* bn1_b = (const float*)d_in[7];
    const float* W2    = (const float*)d_in[8];
    const float* b2    = (const float*)d_in[9];
    const float* bna_g = (const float*)d_in[10];
    const float* bna_b = (const float*)d_in[11];
    const float* bno_g = (const float*)d_in[12];
    const float* bno_b = (const float*)d_in[13];

    const size_t ND = (size_t)N_NODES * DIM;
    float* R0      = (float*)d_ws;                        // N*D floats
    float* R1      = R0 + ND;                             // N*D floats
    float* stats   = R1 + ND;                             // 9 * STSZ floats
    int*   matA    = (int*)(stats + 9 * STSZ);            // NCHUNK*NBUCK
    int*   matoffT = matA + NCHUNK * NBUCK;               // NBUCK*NCHUNK
    int*   btot    = matoffT + NBUCK * NCHUNK;            // NBUCK
    int*   bbase   = btot + NBUCK;                        // NBUCK
    int*   offs    = bbase + NBUCK;                       // N_NODES+1
    uint2* erec    = (uint2*)(((uintptr_t)(offs + N_NODES + 1) + 15) & ~(uintptr_t)15); // E uint2
    unsigned int* erec2 = (unsigned int*)(erec + N_EDGES);     // E uint (4B records)
    unsigned short* wtg = (unsigned short*)(erec2 + N_EDGES);  // 6*128*128 bf16
    float* hout    = (float*)d_out;

    hipMemsetAsync(stats, 0, 9 * STSZ * sizeof(float), stream);
    wt_kernel<<<(6 * DIM * DIM + 255) / 256, 256, 0, stream>>>(W1, W2, wtg);
    conv0_kernel<<<(N_NODES * D8 + 255) / 256, 256, 0, stream>>>(h0, (unsigned short*)R0);

    const int gemm_grid = (N_NODES + 63) / 64;            // 782
    const int agg_grid  = (N_NODES * 16 + 255) / 256;     // 3125

    for (int i = 0; i < N_LAYERS; i++) {
        const int* srcL = src + (size_t)i * N_EDGES;
        const int* dstL = dst + (size_t)i * N_EDGES;
        const float* ewL = ew + (size_t)i * N_EDGES;
        float* st1 = stats + (size_t)(i * 3 + 0) * STSZ;  // NREP x [sum(128)|sq(128)]
        float* stA = stats + (size_t)(i * 3 + 1) * STSZ;
        float* stO = stats + (size_t)(i * 3 + 2) * STSZ;
        const unsigned short* wt1 = wtg + (size_t)i * DIM * DIM;
        const unsigned short* wt2 = wtg + (size_t)(i + 3) * DIM * DIM;

        // ping-pong regions: even layers h/r in R0, odd layers in R1
        float* Re = (i & 1) ? R1 : R0;
        float* Ro = (i & 1) ? R0 : R1;
        unsigned short* hbf = (unsigned short*)Re;        // first half of Re
        unsigned short* rbf = (unsigned short*)Re + ND;   // second half of Re
        float* x1 = Ro;
        float* x2 = Re;                                   // clobbers hbf+rbf (dead)
        unsigned short* ybf = (unsigned short*)Ro;        // next layer's hbf

        // --- binned CSR build (coalesced fill) + per-node gather aggregation ---
        binhist_kernel<<<NCHUNK, 256, 0, stream>>>(dstL, matA);
        colscan_kernel<<<NBUCK, 256, 0, stream>>>(matA, matoffT, btot);
        bucketbase_kernel<<<1, 512, 0, stream>>>(btot, bbase);
        binfill_kernel<<<NCHUNK, 256, 0, stream>>>(srcL, dstL, ewL, matoffT, bbase, erec);
        sortbucket_kernel<<<NBUCK, 256, 0, stream>>>(erec, bbase, btot, erec2, offs);
        agg_kernel<<<agg_grid, 256, 0, stream>>>(hbf, offs, erec2, rbf);

        gemm_kernel<0><<<gemm_grid, 256, 0, stream>>>(
            rbf, nullptr, nullptr, nullptr, nullptr,
            wt1, b1 + (size_t)i * DIM, x1, st1);

        gemm_kernel<1><<<gemm_grid, 256, 0, stream>>>(
            nullptr, x1, st1, bn1_g + (size_t)i * DIM, bn1_b + (size_t)i * DIM,
            wt2, b2 + (size_t)i * DIM, x2, stA);

        bn_stats_kernel<<<1024, 256, 0, stream>>>(
            x2, stA, bna_g + (size_t)i * DIM, bna_b + (size_t)i * DIM, stO);

        if (i == N_LAYERS - 1) {
            bn_final_kernel<1><<<1024, 256, 0, stream>>>(
                x2, stA, bna_g + (size_t)i * DIM, bna_b + (size_t)i * DIM,
                stO, bno_g + (size_t)i * DIM, bno_b + (size_t)i * DIM, hout, nullptr);
        } else {
            bn_final_kernel<0><<<1024, 256, 0, stream>>>(
                x2, stA, bna_g + (size_t)i * DIM, bna_b + (size_t)i * DIM,
                stO, bno_g + (size_t)i * DIM, bno_b + (size_t)i * DIM, nullptr, ybf);
        }
    }
}